// Round 1
// baseline (137.623 us; speedup 1.0000x reference)
//
#include <hip/hip_runtime.h>

#define D 64
#define KCODES 512
#define KHALF 256        // codes staged per half (LDS fits 2 blocks/CU)
#define BLOCK 512        // 8 waves
#define RPB 256          // rows per block (8 waves x 32 rows) -> grid 512 = 2/CU
#define SSTR 257         // half-seg stride in 16B units: 256+1 pad

typedef short  short4_ __attribute__((ext_vector_type(4)));
typedef short  short8  __attribute__((ext_vector_type(8)));
typedef float  f32x4   __attribute__((ext_vector_type(4)));

__device__ __forceinline__ unsigned short bf16rne(float f) {
    union { float f; unsigned u; } a; a.f = f;
    unsigned r = a.u + 0x7FFFu + ((a.u >> 16) & 1u);
    return (unsigned short)(r >> 16);
}
__device__ __forceinline__ void bf16_split(float f, unsigned short& h, unsigned short& l) {
    h = bf16rne(f);
    union { unsigned u; float f; } b; b.u = (unsigned)h << 16;
    l = bf16rne(f - b.f);
}

// Stage one 256-code half of the codebook: coalesced float4 loads, in-register
// bf16 hi/lo split of (-2c) into LDS [seg][code], cc via 16-lane shuffle tree.
// (Same validated math as the r9 prologue A, just half the codes per call.)
#define STAGE_HALF(K0_)                                                          \
    do {                                                                         \
        _Pragma("unroll")                                                        \
        for (int i = 0; i < 8; ++i) {                                            \
            const int e  = i * BLOCK + t;        /* 0..4095 = (code,db) pairs */ \
            const int k  = e >> 4;               /* local code 0..255 */         \
            const int db = e & 15;                                               \
            const int seg = db >> 1, j0 = (db & 1) * 4;                          \
            const float4 q = cbv4[(K0_) * 16 + e];                               \
            short4_ hh, ll;                                                      \
            {                                                                    \
                unsigned short h_, l_;                                           \
                bf16_split(-2.f * q.x, h_, l_); hh[0] = (short)h_; ll[0] = (short)l_; \
                bf16_split(-2.f * q.y, h_, l_); hh[1] = (short)h_; ll[1] = (short)l_; \
                bf16_split(-2.f * q.z, h_, l_); hh[2] = (short)h_; ll[2] = (short)l_; \
                bf16_split(-2.f * q.w, h_, l_); hh[3] = (short)h_; ll[3] = (short)l_; \
            }                                                                    \
            *(short4_*)((short*)&s_cbh[seg * SSTR + k] + j0) = hh;               \
            *(short4_*)((short*)&s_cbl[seg * SSTR + k] + j0) = ll;               \
            float p = fmaf(q.x, q.x, 0.f);                                       \
            p = fmaf(q.y, q.y, p); p = fmaf(q.z, q.z, p); p = fmaf(q.w, q.w, p); \
            p += __shfl_xor(p, 1); p += __shfl_xor(p, 2);                        \
            p += __shfl_xor(p, 4); p += __shfl_xor(p, 8);                        \
            if (db == 0) s_cc[(K0_) + k] = p;                                    \
        }                                                                        \
    } while (0)

// Barrier-free k-loop over one staged half. acc init = cck only: the per-row
// xx term is a constant shift, argmin ordering is invariant to it (exact
// fallback still uses s_xx for true distances).
#define KLOOP(K0_)                                                               \
    do {                                                                         \
        _Pragma("unroll 2")                                                      \
        for (int ct = 0; ct < KHALF / 16; ++ct) {                                \
            const int kl = ct * 16 + col;                                        \
            short8 ch0 = s_cbh[quad * SSTR + kl];                                \
            short8 ch1 = s_cbh[(4 + quad) * SSTR + kl];                          \
            short8 cl0 = s_cbl[quad * SSTR + kl];                                \
            short8 cl1 = s_cbl[(4 + quad) * SSTR + kl];                          \
            const float cck = s_cc[(K0_) + kl];                                  \
            const int   kg  = (K0_) + kl;                                        \
            _Pragma("unroll")                                                    \
            for (int rt = 0; rt < 2; ++rt) {                                     \
                f32x4 acc;                                                       \
                _Pragma("unroll")                                                \
                for (int r = 0; r < 4; ++r) acc[r] = cck;                        \
                acc = __builtin_amdgcn_mfma_f32_16x16x32_bf16(xh[rt][0], ch0, acc, 0, 0, 0); \
                acc = __builtin_amdgcn_mfma_f32_16x16x32_bf16(xl[rt][0], ch0, acc, 0, 0, 0); \
                acc = __builtin_amdgcn_mfma_f32_16x16x32_bf16(xh[rt][0], cl0, acc, 0, 0, 0); \
                acc = __builtin_amdgcn_mfma_f32_16x16x32_bf16(xh[rt][1], ch1, acc, 0, 0, 0); \
                acc = __builtin_amdgcn_mfma_f32_16x16x32_bf16(xl[rt][1], ch1, acc, 0, 0, 0); \
                acc = __builtin_amdgcn_mfma_f32_16x16x32_bf16(xh[rt][1], cl1, acc, 0, 0, 0); \
                _Pragma("unroll")                                                \
                for (int r = 0; r < 4; ++r) {                                    \
                    const int idx = rt * 4 + r;                                  \
                    const float dist = acc[r];                                   \
                    second[idx] = fminf(second[idx], fmaxf(best[idx], dist));    \
                    if (dist < best[idx]) { best[idx] = dist; bis[idx] = kg; }   \
                }                                                                \
            }                                                                    \
        }                                                                        \
    } while (0)

// Single kernel: half-staged codebook (70 KiB LDS -> 2 blocks/CU for phase
// overlap) + GEMM-argmin + hedge + exact fallback + gather.
__global__ __launch_bounds__(BLOCK, 4) void vq_mfma(const float* __restrict__ x,
                                                    const float* __restrict__ cb,
                                                    float* __restrict__ out) {
    __shared__ short8 s_cbh[8 * SSTR];              // 32,896 B
    __shared__ short8 s_cbl[8 * SSTR];              // 32,896 B
    __shared__ float s_cc[KCODES];                  // 2 KiB (full 512, filled by halves)
    __shared__ float s_xx[RPB];
    __shared__ int   s_bi[RPB];
    __shared__ int   s_flag[RPB];
    __shared__ int   s_nflag;

    const int t    = threadIdx.x;
    const int w    = t >> 6;        // wave 0..7
    const int lane = t & 63;
    const int quad = lane >> 4;
    const int col  = lane & 15;
    const float4* xv4  = (const float4*)x;
    const float4* cbv4 = (const float4*)cb;

    if (t == 0) s_nflag = 0;

    // Issue x loads FIRST so HBM latency hides under the codebook-split VALU.
    float4 xq[2][2][2];
    #pragma unroll
    for (int rt = 0; rt < 2; ++rt) {
        const size_t row = (size_t)blockIdx.x * RPB + w * 32 + rt * 16 + col;
        #pragma unroll
        for (int kt = 0; kt < 2; ++kt) {
            xq[rt][kt][0] = xv4[row * 16 + kt * 8 + quad * 2];
            xq[rt][kt][1] = xv4[row * 16 + kt * 8 + quad * 2 + 1];
        }
    }

    STAGE_HALF(0);

    // A-fragments (validated layout: m = lane&15, d = kt*32 + quad*8 + j)
    // + xx via quad-shuffle tree.
    short8 xh[2][2], xl[2][2];
    #pragma unroll
    for (int rt = 0; rt < 2; ++rt) {
        float ssq = 0.f;
        #pragma unroll
        for (int kt = 0; kt < 2; ++kt) {
            const float4 p0 = xq[rt][kt][0];
            const float4 p1 = xq[rt][kt][1];
            float v[8] = {p0.x, p0.y, p0.z, p0.w, p1.x, p1.y, p1.z, p1.w};
            short8 hh, ll;
            #pragma unroll
            for (int j = 0; j < 8; ++j) {
                unsigned short h, l;
                bf16_split(v[j], h, l);
                hh[j] = (short)h; ll[j] = (short)l;
                ssq = fmaf(v[j], v[j], ssq);
            }
            xh[rt][kt] = hh; xl[rt][kt] = ll;
        }
        ssq += __shfl_xor(ssq, 16);
        ssq += __shfl_xor(ssq, 32);
        if (quad == 0) s_xx[w * 32 + rt * 16 + col] = ssq;
    }

    float best[8], second[8]; int bis[8];
    #pragma unroll
    for (int i = 0; i < 8; ++i) { best[i] = __builtin_inff(); second[i] = __builtin_inff(); bis[i] = 0; }

    __syncthreads();        // half 0 + xx ready
    KLOOP(0);
    __syncthreads();        // all readers done with half 0
    STAGE_HALF(KHALF);
    __syncthreads();        // half 1 ready
    KLOOP(KHALF);

    // argmin across the 16 code-lanes per row (validated r4-r9)
    #pragma unroll
    for (int rt = 0; rt < 2; ++rt) {
        #pragma unroll
        for (int r = 0; r < 4; ++r) {
            const int idx = rt * 4 + r;
            float b = best[idx], s2 = second[idx]; int bi = bis[idx];
            #pragma unroll
            for (int off = 1; off < 16; off <<= 1) {
                float ob  = __shfl_xor(b, off);
                int   obi = __shfl_xor(bi, off);
                float os  = __shfl_xor(s2, off);
                s2 = fminf(fminf(s2, os), fmaxf(b, ob));
                if (ob < b || (ob == b && obi < bi)) { b = ob; bi = obi; }
            }
            if (col == 0) {
                const int row = w * 32 + rt * 16 + quad * 4 + r;
                s_bi[row] = bi;
                if (s2 - b < 1e-3f) {
                    int p = atomicAdd(&s_nflag, 1);
                    s_flag[p] = row;
                }
            }
        }
    }
    __syncthreads();

    // exact fp32 re-argmin, thin inverted form (validated r7-r9; ~0.3% rows)
    const int nf = s_nflag;
    for (int i = w; i < nf; i += 8) {
        const int row = s_flag[i];
        const size_t gr = (size_t)blockIdx.x * RPB + row;
        const float xxv = s_xx[row];
        float dot0[8], dot1[8];
        #pragma unroll
        for (int kk = 0; kk < 8; ++kk) { dot0[kk] = 0.f; dot1[kk] = 0.f; }
        for (int db = 0; db < 16; ++db) {
            const float4 xqv = xv4[gr * 16 + db];
            #pragma unroll
            for (int kk = 0; kk < 8; ++kk) {
                const float4 cq = cbv4[(lane * 8 + kk) * 16 + db];
                dot0[kk] = fmaf(xqv.x, cq.x, dot0[kk]);
                dot1[kk] = fmaf(xqv.y, cq.y, dot1[kk]);
                dot0[kk] = fmaf(xqv.z, cq.z, dot0[kk]);
                dot1[kk] = fmaf(xqv.w, cq.w, dot1[kk]);
            }
        }
        float b = __builtin_inff(); int bi = 0;
        #pragma unroll
        for (int kk = 0; kk < 8; ++kk) {
            const int k = lane * 8 + kk;
            const float dist = (xxv - 2.f * (dot0[kk] + dot1[kk])) + s_cc[k];
            if (dist < b) { b = dist; bi = k; }
        }
        #pragma unroll
        for (int off = 1; off < 64; off <<= 1) {
            float ob  = __shfl_xor(b, off);
            int   obi = __shfl_xor(bi, off);
            if (ob < b || (ob == b && obi < bi)) { b = ob; bi = obi; }
        }
        if (lane == 0) s_bi[row] = bi;
    }
    __syncthreads();

    // coalesced gather+store (validated r2/r4-r9)
    float4* outv = (float4*)out + (size_t)blockIdx.x * (RPB * 16);
    #pragma unroll
    for (int j = 0; j < RPB * 16 / BLOCK; ++j) {
        const int f4 = j * BLOCK + t;
        const int r  = f4 >> 4;
        const int q  = f4 & 15;
        outv[f4] = cbv4[s_bi[r] * 16 + q];
    }
}

extern "C" void kernel_launch(void* const* d_in, const int* in_sizes, int n_in,
                              void* d_out, int out_size, void* d_ws, size_t ws_size,
                              hipStream_t stream) {
    const float* x  = (const float*)d_in[0];   // 131072 x 64
    const float* cb = (const float*)d_in[1];   // 512 x 64
    float* out = (float*)d_out;

    const int N = in_sizes[0] / D;             // 131072
    vq_mfma<<<N / RPB, BLOCK, 0, stream>>>(x, cb, out);
}